// Round 6
// baseline (511.912 us; speedup 1.0000x reference)
//
#include <hip/hip_runtime.h>
#include <cstdint>

// R11: coalesced C-write via LDS bounce. Theory: 5 different K-loop
// schedules (R5-R9) gave identical gemm times -> limiter is schedule-
// insensitive. The untouched cost: C/D fragment layout scatters stores
// as 64B(f32)/32B(f16) segments at 4KB stride, ~65MB/kernel, 4x more
// write-intense than the 4096^3 ladder at K=1024. Fix: stage each 64-row
// half of the C tile into dead sA/sB LDS ([64][128] f32, g-XOR slot
// swizzle, conflict-free), then stream out 512B(f32)/256B(f16) rows.
// Bias+ReLU folded into the read phase; STATS unchanged; math identical.

#define L2E 1.4426950408889634f

typedef _Float16 half8 __attribute__((ext_vector_type(8)));
typedef _Float16 half4v __attribute__((ext_vector_type(4)));
typedef float f32x4 __attribute__((ext_vector_type(4)));

__device__ __forceinline__ void gl_lds16(const void* g, void* l) {
  __builtin_amdgcn_global_load_lds(
      (const __attribute__((address_space(1))) unsigned int*)g,
      (__attribute__((address_space(3))) unsigned int*)l, 16, 0, 0);
}

// C(M,N) = op( X(M,K) @ Y(N,K)^T + bias ), op = relu if BIASRELU.
// 1D grid + XCD swizzle (id&7 -> XCD). shalf>0: merged two-gemm launch
// (s >= shalf uses X2/Y2/C2). STATS: emit row/col softmax partials.
template<int K, bool BIASRELU, bool STATS, typename OutT>
__global__ __launch_bounds__(256, 2)
void gemm_k(const _Float16* __restrict__ X, const _Float16* __restrict__ Y,
            const float* __restrict__ bias, OutT* __restrict__ C, int N,
            long xbs, long ybs, long cbs, int gm, int gn, int gz,
            float* __restrict__ prm, float* __restrict__ prs,
            float* __restrict__ pcm, float* __restrict__ pcs,
            const _Float16* __restrict__ X2, const _Float16* __restrict__ Y2,
            OutT* __restrict__ C2, int shalf)
{
  __shared__ __align__(16) _Float16 sAB[2][128 * 64];
  _Float16* sA = sAB[0];
  _Float16* sB = sAB[1];
  const int t = threadIdx.x;
  const int lane = t & 63, w = t >> 6;
  const int wr = w >> 1, wc = w & 1;
  const int lm = lane & 15, g = lane >> 4;
  const int xr = lane & 7;  // == (fragment row) & 7

  // swizzle decode
  const int id = blockIdx.x;
  const int c = id & 7;
  int s = id >> 3;
  if (shalf && s >= shalf) { s -= shalf; X = X2; Y = Y2; C = C2; }
  int m, n, bz;
  if (gz == 1) {
    int q = s / gn;
    n = s - q * gn;
    m = c * (gm >> 3) + q;
    bz = 0;
  } else {
    int tpb = gm * gn;
    int bq = s / tpb;
    bz = c * (gz >> 3) + bq;
    int r = s - bq * tpb;
    m = r / gn;
    n = r - m * gn;
  }
  const int m0 = m * 128, n0 = n * 128;

  X += (size_t)bz * xbs;
  Y += (size_t)bz * ybs;
  C += (size_t)bz * cbs;

  // staging constants: chunk cid = r*256+t -> LDS row = r*32 + (t>>3),
  // pos = t&7; global k-offset = (pos ^ (row&7))*8  (row&7 == (t>>3)&7)
  const int stg_row = t >> 3;
  const int stg_koff = (((t & 7) ^ ((t >> 3) & 7)) << 3);

  // fragment LDS bases (f16 units): row*64 + ((ks*4+g)^xr)*8
  int arow[4], brow[4], axo[2];
#pragma unroll
  for (int i = 0; i < 4; ++i) {
    arow[i] = (wr * 64 + i * 16 + lm) * 64;
    brow[i] = (wc * 64 + i * 16 + lm) * 64;
  }
  axo[0] = ((0 * 4 + g) ^ xr) * 8;
  axo[1] = ((1 * 4 + g) ^ xr) * 8;

  f32x4 acc[4][4] = {};

  for (int kt = 0; kt < K; kt += 64) {
    __syncthreads();
#pragma unroll
    for (int r = 0; r < 4; ++r) {
      int row = r * 32 + stg_row;
      gl_lds16(X + (size_t)(m0 + row) * K + kt + stg_koff, sA + (r * 256 + t) * 8);
    }
#pragma unroll
    for (int r = 0; r < 4; ++r) {
      int row = r * 32 + stg_row;
      gl_lds16(Y + (size_t)(n0 + row) * K + kt + stg_koff, sB + (r * 256 + t) * 8);
    }
    __syncthreads();

    half8 af[4], bf[4];
#pragma unroll
    for (int ks = 0; ks < 2; ++ks) {
#pragma unroll
      for (int mi = 0; mi < 4; ++mi)
        af[mi] = *(const half8*)(sA + arow[mi] + axo[ks]);
#pragma unroll
      for (int ni = 0; ni < 4; ++ni)
        bf[ni] = *(const half8*)(sB + brow[ni] + axo[ks]);
#pragma unroll
      for (int mi = 0; mi < 4; ++mi)
#pragma unroll
        for (int ni = 0; ni < 4; ++ni)
          acc[mi][ni] = __builtin_amdgcn_mfma_f32_16x16x32_f16(af[mi], bf[ni], acc[mi][ni], 0, 0, 0);
    }
  }

  // ---- coalesced C write: LDS bounce, 2 halves of 64 rows ----
  // Stage layout: epi[r][col ^ ((r>>2 & 3)<<2)] (f32). The XOR spreads the
  // 4 g-lanes (rows 4 apart) across 4 distinct 4-col slots -> conflict-free
  // b32 writes; reads of 4 consecutive cols stay a single aligned float4.
  {
    float* epi = (float*)sAB;               // 64*128 f32 = 32 KB
    const int erow = t >> 5;                // 0..7
    const int ecol4 = (t & 31) * 4;         // 0..124
    __syncthreads();                        // all MFMA fragment reads done
#pragma unroll
    for (int h = 0; h < 2; ++h) {
      if (wr == h) {
#pragma unroll
        for (int mi = 0; mi < 4; ++mi) {
          const int r = mi * 16 + g * 4;    // +q below; r>>2 = mi*4+g
          const int xo = ((mi * 4 + g) & 3) << 2;
#pragma unroll
          for (int ni = 0; ni < 4; ++ni) {
            const int col = (wc * 64 + ni * 16 + lm) ^ xo;
#pragma unroll
            for (int q = 0; q < 4; ++q)
              epi[(r + q) * 128 + col] = acc[mi][ni][q];
          }
        }
      }
      __syncthreads();
#pragma unroll
      for (int r8 = 0; r8 < 8; ++r8) {
        const int row = r8 * 8 + erow;
        const int xo = ((row >> 2) & 3) << 2;
        const int gc = n0 + ecol4;
        float4 v = *(const float4*)(epi + row * 128 + (ecol4 ^ xo));
        if constexpr (BIASRELU) {
          const float4 bv = *(const float4*)(bias + gc);
          v.x = fmaxf(v.x + bv.x, 0.f); v.y = fmaxf(v.y + bv.y, 0.f);
          v.z = fmaxf(v.z + bv.z, 0.f); v.w = fmaxf(v.w + bv.w, 0.f);
        }
        if constexpr (sizeof(OutT) == 2) {
          half4v o;
          o[0] = (_Float16)v.x; o[1] = (_Float16)v.y;
          o[2] = (_Float16)v.z; o[3] = (_Float16)v.w;
          *(half4v*)((_Float16*)C + (size_t)(m0 + h * 64 + row) * N + gc) = o;
        } else {
          *(float4*)((float*)C + (size_t)(m0 + h * 64 + row) * N + gc) = v;
        }
      }
      __syncthreads();
    }
  }

  if constexpr (STATS) {
    __shared__ float sRm[256], sRs[256], sCm[256], sCs[256];
    float rowm[4][4], rows_[4][4];
#pragma unroll
    for (int mi = 0; mi < 4; ++mi) {
#pragma unroll
      for (int q = 0; q < 4; ++q) {
        float mloc = fmaxf(fmaxf(acc[mi][0][q], acc[mi][1][q]),
                           fmaxf(acc[mi][2][q], acc[mi][3][q]));
#pragma unroll
        for (int msk = 1; msk < 16; msk <<= 1)
          mloc = fmaxf(mloc, __shfl_xor(mloc, msk));
        float sl = 0.f;
#pragma unroll
        for (int ni = 0; ni < 4; ++ni)
          sl += exp2f((acc[mi][ni][q] - mloc) * L2E);
#pragma unroll
        for (int msk = 1; msk < 16; msk <<= 1)
          sl += __shfl_xor(sl, msk);
        rowm[mi][q] = mloc;
        rows_[mi][q] = sl;
      }
    }
    if (lm == 0) {
#pragma unroll
      for (int mi = 0; mi < 4; ++mi)
#pragma unroll
        for (int q = 0; q < 4; ++q) {
          int rloc = wr * 64 + mi * 16 + (lane >> 4) * 4 + q;
          sRm[wc * 128 + rloc] = rowm[mi][q];
          sRs[wc * 128 + rloc] = rows_[mi][q];
        }
    }
#pragma unroll
    for (int ni = 0; ni < 4; ++ni) {
      float mloc = -3.0e38f;
#pragma unroll
      for (int mi = 0; mi < 4; ++mi)
#pragma unroll
        for (int q = 0; q < 4; ++q)
          mloc = fmaxf(mloc, acc[mi][ni][q]);
      mloc = fmaxf(mloc, __shfl_xor(mloc, 16));
      mloc = fmaxf(mloc, __shfl_xor(mloc, 32));
      float sl = 0.f;
#pragma unroll
      for (int mi = 0; mi < 4; ++mi)
#pragma unroll
        for (int q = 0; q < 4; ++q)
          sl += exp2f((acc[mi][ni][q] - mloc) * L2E);
      sl += __shfl_xor(sl, 16);
      sl += __shfl_xor(sl, 32);
      if ((lane >> 4) == 0) {
        int cloc = wc * 64 + ni * 16 + lm;
        sCm[wr * 128 + cloc] = mloc;
        sCs[wr * 128 + cloc] = sl;
      }
    }
    __syncthreads();
    if (t < 128) {
      float m1 = sRm[t], m2 = sRm[128 + t];
      float M = fmaxf(m1, m2);
      float S = sRs[t] * exp2f((m1 - M) * L2E) + sRs[128 + t] * exp2f((m2 - M) * L2E);
      size_t o = ((size_t)bz * 8 + n) * 1024 + m0 + t;
      prm[o] = M;
      prs[o] = S;
    } else {
      int u = t - 128;
      float m1 = sCm[u], m2 = sCm[128 + u];
      float M = fmaxf(m1, m2);
      float S = sCs[u] * exp2f((m1 - M) * L2E) + sCs[128 + u] * exp2f((m2 - M) * L2E);
      size_t o = ((size_t)bz * 8 + m) * 1024 + n0 + u;
      pcm[o] = M;
      pcs[o] = S;
    }
  }
}

// read e 64x64 tile once; combine partial stats inline; write P (row-softmax)
// and PT (col-softmax, transposed via LDS)
__global__ __launch_bounds__(256)
void softmax_apply(const float* __restrict__ e,
                   const float* __restrict__ prm, const float* __restrict__ prs,
                   const float* __restrict__ pcm, const float* __restrict__ pcs,
                   _Float16* __restrict__ P, _Float16* __restrict__ PT)
{
  __shared__ _Float16 tl[64][65];
  __shared__ float sRm[64], sRi[64], sCm[64], sCi[64];
  const int bz = blockIdx.z;
  const int r0 = blockIdx.y * 64, c0 = blockIdx.x * 64;
  const size_t bo = (size_t)bz * 1048576;
  const int t = threadIdx.x;

  if (t < 128) {
    const int isCol = t >> 6;
    const int u = t & 63;
    const float* pm = isCol ? pcm : prm;
    const float* ps = isCol ? pcs : prs;
    const int pos = (isCol ? c0 : r0) + u;
    float mj[8], sj[8];
#pragma unroll
    for (int j = 0; j < 8; ++j) {
      size_t o = ((size_t)bz * 8 + j) * 1024 + pos;
      mj[j] = pm[o];
      sj[j] = ps[o];
    }
    float M = -3.0e38f;
#pragma unroll
    for (int j = 0; j < 8; ++j) M = fmaxf(M, mj[j]);
    float S = 0.f;
#pragma unroll
    for (int j = 0; j < 8; ++j) S += sj[j] * exp2f((mj[j] - M) * L2E);
    if (isCol) { sCm[u] = M; sCi[u] = 1.f / S; }
    else       { sRm[u] = M; sRi[u] = 1.f / S; }
  }
  __syncthreads();

#pragma unroll
  for (int p = 0; p < 4; ++p) {
    int idx = p * 256 + t;
    int row = idx >> 4, col4 = (idx & 15) * 4;
    float4 v = *(const float4*)(e + bo + (size_t)(r0 + row) * 1024 + c0 + col4);
    float vv[4] = {v.x, v.y, v.z, v.w};
    const float mrow = sRm[row];
    const float irow = sRi[row];
    half4v op;
#pragma unroll
    for (int j = 0; j < 4; ++j) {
      op[j] = (_Float16)(exp2f((vv[j] - mrow) * L2E) * irow);
      tl[col4 + j][row] = (_Float16)(exp2f((vv[j] - sCm[col4 + j]) * L2E) * sCi[col4 + j]);
    }
    *(half4v*)(P + bo + (size_t)(r0 + row) * 1024 + c0 + col4) = op;
  }
  __syncthreads();
#pragma unroll
  for (int p = 0; p < 4; ++p) {
    int idx = p * 256 + t;
    int trow = idx >> 4, tcol4 = (idx & 15) * 4;
    half4v ov;
#pragma unroll
    for (int j = 0; j < 4; ++j) ov[j] = tl[trow][tcol4 + j];
    *(half4v*)(PT + bo + (size_t)(c0 + trow) * 1024 + r0 + tcol4) = ov;
  }
}

// fp32 (R,C) -> f16 (C,R). DUAL via z >= nb, with independent dims R2,C2
// for the second tensor (lets W1 (768x1024) + W2 (1024x1024) share one
// launch). OOB rows guarded.
__global__ __launch_bounds__(256)
void transpose_cvt(const float* __restrict__ in1, _Float16* __restrict__ out1,
                   const float* __restrict__ in2, _Float16* __restrict__ out2,
                   int R, int C, int nb, int R2, int C2)
{
  __shared__ float tl[32][33];
  int z = blockIdx.z;
  const float* in = in1;
  _Float16* out = out1;
  if (z >= nb) { z -= nb; in = in2; out = out2; R = R2; C = C2; }
  const size_t bo = (size_t)z * R * C;
  int x = blockIdx.x * 32 + threadIdx.x;
  int y0 = blockIdx.y * 32;
  for (int i = threadIdx.y; i < 32; i += 8)
    tl[i][threadIdx.x] = (x < C && y0 + i < R) ? in[bo + (size_t)(y0 + i) * C + x] : 0.f;
  __syncthreads();
  int xo = y0 + threadIdx.x;
  int c0 = blockIdx.x * 32;
  if (xo < R)
    for (int i = threadIdx.y; i < 32; i += 8)
      if (c0 + i < C)
        out[bo + (size_t)(c0 + i) * R + xo] = (_Float16)tl[threadIdx.x][i];
}

__global__ __launch_bounds__(256)
void cvt_f16_2(const float* __restrict__ inA, const float* __restrict__ inB,
               _Float16* __restrict__ oA, _Float16* __restrict__ oB, int n4)
{
  int i = blockIdx.x * 256 + threadIdx.x;
  const float* in = inA;
  _Float16* out = oA;
  if (i >= n4) { i -= n4; in = inB; out = oB; }
  float4 v = ((const float4*)in)[i];
  half4v o;
  o[0] = (_Float16)v.x; o[1] = (_Float16)v.y; o[2] = (_Float16)v.z; o[3] = (_Float16)v.w;
  ((half4v*)out)[i] = o;
}

extern "C" void kernel_launch(void* const* d_in, const int* in_sizes, int n_in,
                              void* d_out, int out_size, void* d_ws, size_t ws_size,
                              hipStream_t stream)
{
  const float* A  = (const float*)d_in[0];
  const float* B  = (const float*)d_in[1];
  const float* W1 = (const float*)d_in[2];
  const float* b1 = (const float*)d_in[3];
  const float* W2 = (const float*)d_in[4];
  const float* b2 = (const float*)d_in[5];
  float* out = (float*)d_out;

  char* ws = (char*)d_ws;
  _Float16* Af  = (_Float16*)(ws + 0);           // X = Af||Bf = (32768,768)
  _Float16* Bf  = (_Float16*)(ws + 25165824);
  _Float16* W1t = (_Float16*)(ws + 50331648);
  _Float16* W2t = (_Float16*)(ws + 51904512);
  // partials overwrite W1t/W2t (dead after gemm2; e-gemm runs later)
  float*    prm = (float*)   (ws + 50331648);
  float*    prs = (float*)   (ws + 50331648 + 524288);
  float*    pcm = (float*)   (ws + 50331648 + 1048576);
  float*    pcs = (float*)   (ws + 50331648 + 1572864);
  _Float16* fAB = (_Float16*)(ws + 54001664);    // (32768,1024)
  _Float16* P   = (_Float16*)(ws + 54001664);    // alias fAB (dead after e-gemm)
  _Float16* PT  = (_Float16*)(ws + 87556096);
  _Float16* h   = (_Float16*)(ws + 121110528);   // (32768,1024)
  float*    e   = (float*)   (ws + 121110528);   // alias h (dead after gemm2)
  _Float16* fA = fAB;
  _Float16* fB = fAB + 16777216;
  _Float16* At = Af;
  _Float16* Bt = Bf;

  dim3 blk(256);
  dim3 tblk(32, 8);

  cvt_f16_2<<<24576, blk, 0, stream>>>(A, B, Af, Bf, 3145728);
  // W1 (768,1024) and W2 (1024,1024) transposed+cvt in ONE launch
  transpose_cvt<<<dim3(32, 32, 2), tblk, 0, stream>>>(
      W1, W1t, W2, W2t, 768, 1024, 1, 1024, 1024);

  // h = relu([Af;Bf] @ W1 + b1)  (32768x1024), gm=256 gn=8
  gemm_k<768, true, false, _Float16><<<2048, blk, 0, stream>>>(
      Af, W1t, b1, h, 1024, 0, 0, 0, 256, 8, 1,
      nullptr, nullptr, nullptr, nullptr, nullptr, nullptr, nullptr, 0);
  // At/Bt (f16 (768,1024) per batch) — Af/Bf dead after gemm1
  transpose_cvt<<<dim3(24, 32, 32), tblk, 0, stream>>>(
      A, At, B, Bt, 1024, 768, 16, 1024, 768);
  // fAB = relu(h @ W2 + b2)
  gemm_k<1024, true, false, _Float16><<<2048, blk, 0, stream>>>(
      h, W2t, b2, fAB, 1024, 0, 0, 0, 256, 8, 1,
      nullptr, nullptr, nullptr, nullptr, nullptr, nullptr, nullptr, 0);

  // e = fA @ fB^T (batched fp32) + softmax partials in epilogue
  gemm_k<1024, false, true, float><<<1024, blk, 0, stream>>>(
      fA, fB, nullptr, e, 1024, 1048576L, 1048576L, 1048576L, 8, 8, 16,
      prm, prs, pcm, pcs, nullptr, nullptr, nullptr, 0);

  softmax_apply<<<dim3(16, 16, 16), blk, 0, stream>>>(e, prm, prs, pcm, pcs, P, PT);

  // beta = P @ Bt -> out[0:12582912]; alpha = PT @ At -> out[12582912:]
  // merged launch: gm=8 gn=6 gz=16 per half, shalf = 2*48 = 96
  gemm_k<1024, false, false, float><<<1536, blk, 0, stream>>>(
      P, Bt, nullptr, out, 768, 1048576L, 786432L, 786432L, 8, 6, 16,
      nullptr, nullptr, nullptr, nullptr, PT, At, out + 12582912, 96);
}

// Round 7
// 504.860 us; speedup vs baseline: 1.0140x; 1.0140x over previous
//
#include <hip/hip_runtime.h>
#include <cstdint>

// R12: revert R11 bounce (falsified: WRITE_SIZE was already minimal; bounce
// added 1M bank conflicts, +5us). New theory from per-gemm rates: weight-
// operand gemms (gemm1/2) hit the structure ceiling (~850 TF) because W*t
// (<=2MB) is L2-resident; e-gemm (419 TF) and final gemm (~644 TF) thrash:
// at 4 blocks/CU an XCD holds TWO batches of operands (8MB) vs 4MB L2, so
// every K-step stages from L3 (512MB/82us = 6.2 TB/s aggregate = L3 rate,
// FETCH only 41MB). Fix: cap !BIASRELU gemms at 2 blocks/CU via +24KB dead
// LDS -> resident set per XCD = ONE batch (fA+fB = 4MB = L2). Single
// variable; BIASRELU instantiations keep LDS exactly 32768.

#define L2E 1.4426950408889634f

typedef _Float16 half8 __attribute__((ext_vector_type(8)));
typedef _Float16 half4v __attribute__((ext_vector_type(4)));
typedef float f32x4 __attribute__((ext_vector_type(4)));

__device__ __forceinline__ void gl_lds16(const void* g, void* l) {
  __builtin_amdgcn_global_load_lds(
      (const __attribute__((address_space(1))) unsigned int*)g,
      (__attribute__((address_space(3))) unsigned int*)l, 16, 0, 0);
}

// C(M,N) = op( X(M,K) @ Y(N,K)^T + bias ), op = relu if BIASRELU.
// 1D grid + XCD swizzle (id&7 -> XCD). shalf>0: merged two-gemm launch
// (s >= shalf uses X2/Y2/C2). STATS: emit row/col softmax partials.
template<int K, bool BIASRELU, bool STATS, typename OutT>
__global__ __launch_bounds__(256, 2)
void gemm_k(const _Float16* __restrict__ X, const _Float16* __restrict__ Y,
            const float* __restrict__ bias, OutT* __restrict__ C, int N,
            long xbs, long ybs, long cbs, int gm, int gn, int gz,
            float* __restrict__ prm, float* __restrict__ prs,
            float* __restrict__ pcm, float* __restrict__ pcs,
            const _Float16* __restrict__ X2, const _Float16* __restrict__ Y2,
            OutT* __restrict__ C2, int shalf)
{
  __shared__ __align__(16) _Float16 sA[128 * 64];
  __shared__ __align__(16) _Float16 sB[128 * 64];
  const int t = threadIdx.x;

  // Occupancy cap for batched (non-weight) gemms: +24KB dead LDS ->
  // 2 blocks/CU -> per-XCD resident working set fits the 4MB L2.
  if constexpr (!BIASRELU) {
    __shared__ volatile float l2cap[6144];
    if (gm == -31415) l2cap[t] = (float)t;             // never true
    if (gm == -31416) ((float*)C)[0] = l2cap[t];       // keep alive
  }

  const int lane = t & 63, w = t >> 6;
  const int wr = w >> 1, wc = w & 1;
  const int lm = lane & 15, g = lane >> 4;
  const int xr = lane & 7;  // == (fragment row) & 7

  // swizzle decode
  const int id = blockIdx.x;
  const int c = id & 7;
  int s = id >> 3;
  if (shalf && s >= shalf) { s -= shalf; X = X2; Y = Y2; C = C2; }
  int m, n, bz;
  if (gz == 1) {
    int q = s / gn;
    n = s - q * gn;
    m = c * (gm >> 3) + q;
    bz = 0;
  } else {
    int tpb = gm * gn;
    int bq = s / tpb;
    bz = c * (gz >> 3) + bq;
    int r = s - bq * tpb;
    m = r / gn;
    n = r - m * gn;
  }
  const int m0 = m * 128, n0 = n * 128;

  X += (size_t)bz * xbs;
  Y += (size_t)bz * ybs;
  C += (size_t)bz * cbs;

  // staging constants: chunk cid = r*256+t -> LDS row = r*32 + (t>>3),
  // pos = t&7; global k-offset = (pos ^ (row&7))*8  (row&7 == (t>>3)&7)
  const int stg_row = t >> 3;
  const int stg_koff = (((t & 7) ^ ((t >> 3) & 7)) << 3);

  // fragment LDS bases (f16 units): row*64 + ((ks*4+g)^xr)*8
  int arow[4], brow[4], axo[2];
#pragma unroll
  for (int i = 0; i < 4; ++i) {
    arow[i] = (wr * 64 + i * 16 + lm) * 64;
    brow[i] = (wc * 64 + i * 16 + lm) * 64;
  }
  axo[0] = ((0 * 4 + g) ^ xr) * 8;
  axo[1] = ((1 * 4 + g) ^ xr) * 8;

  f32x4 acc[4][4] = {};

  for (int kt = 0; kt < K; kt += 64) {
    __syncthreads();
#pragma unroll
    for (int r = 0; r < 4; ++r) {
      int row = r * 32 + stg_row;
      gl_lds16(X + (size_t)(m0 + row) * K + kt + stg_koff, sA + (r * 256 + t) * 8);
    }
#pragma unroll
    for (int r = 0; r < 4; ++r) {
      int row = r * 32 + stg_row;
      gl_lds16(Y + (size_t)(n0 + row) * K + kt + stg_koff, sB + (r * 256 + t) * 8);
    }
    __syncthreads();

    half8 af[4], bf[4];
#pragma unroll
    for (int ks = 0; ks < 2; ++ks) {
#pragma unroll
      for (int mi = 0; mi < 4; ++mi)
        af[mi] = *(const half8*)(sA + arow[mi] + axo[ks]);
#pragma unroll
      for (int ni = 0; ni < 4; ++ni)
        bf[ni] = *(const half8*)(sB + brow[ni] + axo[ks]);
#pragma unroll
      for (int mi = 0; mi < 4; ++mi)
#pragma unroll
        for (int ni = 0; ni < 4; ++ni)
          acc[mi][ni] = __builtin_amdgcn_mfma_f32_16x16x32_f16(af[mi], bf[ni], acc[mi][ni], 0, 0, 0);
    }
  }

#pragma unroll
  for (int mi = 0; mi < 4; ++mi) {
    const int rbase = m0 + wr * 64 + mi * 16 + (lane >> 4) * 4;
#pragma unroll
    for (int ni = 0; ni < 4; ++ni) {
      const int col = n0 + wc * 64 + ni * 16 + lm;
      float bv = 0.f;
      if constexpr (BIASRELU) bv = bias[col];
#pragma unroll
      for (int q = 0; q < 4; ++q) {
        float v = acc[mi][ni][q] + bv;
        if constexpr (BIASRELU) v = fmaxf(v, 0.f);
        C[(size_t)(rbase + q) * N + col] = (OutT)v;
      }
    }
  }

  if constexpr (STATS) {
    __shared__ float sRm[256], sRs[256], sCm[256], sCs[256];
    float rowm[4][4], rows_[4][4];
#pragma unroll
    for (int mi = 0; mi < 4; ++mi) {
#pragma unroll
      for (int q = 0; q < 4; ++q) {
        float mloc = fmaxf(fmaxf(acc[mi][0][q], acc[mi][1][q]),
                           fmaxf(acc[mi][2][q], acc[mi][3][q]));
#pragma unroll
        for (int msk = 1; msk < 16; msk <<= 1)
          mloc = fmaxf(mloc, __shfl_xor(mloc, msk));
        float sl = 0.f;
#pragma unroll
        for (int ni = 0; ni < 4; ++ni)
          sl += exp2f((acc[mi][ni][q] - mloc) * L2E);
#pragma unroll
        for (int msk = 1; msk < 16; msk <<= 1)
          sl += __shfl_xor(sl, msk);
        rowm[mi][q] = mloc;
        rows_[mi][q] = sl;
      }
    }
    if (lm == 0) {
#pragma unroll
      for (int mi = 0; mi < 4; ++mi)
#pragma unroll
        for (int q = 0; q < 4; ++q) {
          int rloc = wr * 64 + mi * 16 + (lane >> 4) * 4 + q;
          sRm[wc * 128 + rloc] = rowm[mi][q];
          sRs[wc * 128 + rloc] = rows_[mi][q];
        }
    }
#pragma unroll
    for (int ni = 0; ni < 4; ++ni) {
      float mloc = -3.0e38f;
#pragma unroll
      for (int mi = 0; mi < 4; ++mi)
#pragma unroll
        for (int q = 0; q < 4; ++q)
          mloc = fmaxf(mloc, acc[mi][ni][q]);
      mloc = fmaxf(mloc, __shfl_xor(mloc, 16));
      mloc = fmaxf(mloc, __shfl_xor(mloc, 32));
      float sl = 0.f;
#pragma unroll
      for (int mi = 0; mi < 4; ++mi)
#pragma unroll
        for (int q = 0; q < 4; ++q)
          sl += exp2f((acc[mi][ni][q] - mloc) * L2E);
      sl += __shfl_xor(sl, 16);
      sl += __shfl_xor(sl, 32);
      if ((lane >> 4) == 0) {
        int cloc = wc * 64 + ni * 16 + lm;
        sCm[wr * 128 + cloc] = mloc;
        sCs[wr * 128 + cloc] = sl;
      }
    }
    __syncthreads();
    if (t < 128) {
      float m1 = sRm[t], m2 = sRm[128 + t];
      float M = fmaxf(m1, m2);
      float S = sRs[t] * exp2f((m1 - M) * L2E) + sRs[128 + t] * exp2f((m2 - M) * L2E);
      size_t o = ((size_t)bz * 8 + n) * 1024 + m0 + t;
      prm[o] = M;
      prs[o] = S;
    } else {
      int u = t - 128;
      float m1 = sCm[u], m2 = sCm[128 + u];
      float M = fmaxf(m1, m2);
      float S = sCs[u] * exp2f((m1 - M) * L2E) + sCs[128 + u] * exp2f((m2 - M) * L2E);
      size_t o = ((size_t)bz * 8 + m) * 1024 + n0 + u;
      pcm[o] = M;
      pcs[o] = S;
    }
  }
}

// read e 64x64 tile once; combine partial stats inline; write P (row-softmax)
// and PT (col-softmax, transposed via LDS)
__global__ __launch_bounds__(256)
void softmax_apply(const float* __restrict__ e,
                   const float* __restrict__ prm, const float* __restrict__ prs,
                   const float* __restrict__ pcm, const float* __restrict__ pcs,
                   _Float16* __restrict__ P, _Float16* __restrict__ PT)
{
  __shared__ _Float16 tl[64][65];
  __shared__ float sRm[64], sRi[64], sCm[64], sCi[64];
  const int bz = blockIdx.z;
  const int r0 = blockIdx.y * 64, c0 = blockIdx.x * 64;
  const size_t bo = (size_t)bz * 1048576;
  const int t = threadIdx.x;

  if (t < 128) {
    const int isCol = t >> 6;
    const int u = t & 63;
    const float* pm = isCol ? pcm : prm;
    const float* ps = isCol ? pcs : prs;
    const int pos = (isCol ? c0 : r0) + u;
    float mj[8], sj[8];
#pragma unroll
    for (int j = 0; j < 8; ++j) {
      size_t o = ((size_t)bz * 8 + j) * 1024 + pos;
      mj[j] = pm[o];
      sj[j] = ps[o];
    }
    float M = -3.0e38f;
#pragma unroll
    for (int j = 0; j < 8; ++j) M = fmaxf(M, mj[j]);
    float S = 0.f;
#pragma unroll
    for (int j = 0; j < 8; ++j) S += sj[j] * exp2f((mj[j] - M) * L2E);
    if (isCol) { sCm[u] = M; sCi[u] = 1.f / S; }
    else       { sRm[u] = M; sRi[u] = 1.f / S; }
  }
  __syncthreads();

#pragma unroll
  for (int p = 0; p < 4; ++p) {
    int idx = p * 256 + t;
    int row = idx >> 4, col4 = (idx & 15) * 4;
    float4 v = *(const float4*)(e + bo + (size_t)(r0 + row) * 1024 + c0 + col4);
    float vv[4] = {v.x, v.y, v.z, v.w};
    const float mrow = sRm[row];
    const float irow = sRi[row];
    half4v op;
#pragma unroll
    for (int j = 0; j < 4; ++j) {
      op[j] = (_Float16)(exp2f((vv[j] - mrow) * L2E) * irow);
      tl[col4 + j][row] = (_Float16)(exp2f((vv[j] - sCm[col4 + j]) * L2E) * sCi[col4 + j]);
    }
    *(half4v*)(P + bo + (size_t)(r0 + row) * 1024 + c0 + col4) = op;
  }
  __syncthreads();
#pragma unroll
  for (int p = 0; p < 4; ++p) {
    int idx = p * 256 + t;
    int trow = idx >> 4, tcol4 = (idx & 15) * 4;
    half4v ov;
#pragma unroll
    for (int j = 0; j < 4; ++j) ov[j] = tl[trow][tcol4 + j];
    *(half4v*)(PT + bo + (size_t)(c0 + trow) * 1024 + r0 + tcol4) = ov;
  }
}

// fp32 (R,C) -> f16 (C,R). DUAL via z >= nb, with independent dims R2,C2
// for the second tensor (lets W1 (768x1024) + W2 (1024x1024) share one
// launch). OOB rows guarded.
__global__ __launch_bounds__(256)
void transpose_cvt(const float* __restrict__ in1, _Float16* __restrict__ out1,
                   const float* __restrict__ in2, _Float16* __restrict__ out2,
                   int R, int C, int nb, int R2, int C2)
{
  __shared__ float tl[32][33];
  int z = blockIdx.z;
  const float* in = in1;
  _Float16* out = out1;
  if (z >= nb) { z -= nb; in = in2; out = out2; R = R2; C = C2; }
  const size_t bo = (size_t)z * R * C;
  int x = blockIdx.x * 32 + threadIdx.x;
  int y0 = blockIdx.y * 32;
  for (int i = threadIdx.y; i < 32; i += 8)
    tl[i][threadIdx.x] = (x < C && y0 + i < R) ? in[bo + (size_t)(y0 + i) * C + x] : 0.f;
  __syncthreads();
  int xo = y0 + threadIdx.x;
  int c0 = blockIdx.x * 32;
  if (xo < R)
    for (int i = threadIdx.y; i < 32; i += 8)
      if (c0 + i < C)
        out[bo + (size_t)(c0 + i) * R + xo] = (_Float16)tl[threadIdx.x][i];
}

__global__ __launch_bounds__(256)
void cvt_f16_2(const float* __restrict__ inA, const float* __restrict__ inB,
               _Float16* __restrict__ oA, _Float16* __restrict__ oB, int n4)
{
  int i = blockIdx.x * 256 + threadIdx.x;
  const float* in = inA;
  _Float16* out = oA;
  if (i >= n4) { i -= n4; in = inB; out = oB; }
  float4 v = ((const float4*)in)[i];
  half4v o;
  o[0] = (_Float16)v.x; o[1] = (_Float16)v.y; o[2] = (_Float16)v.z; o[3] = (_Float16)v.w;
  ((half4v*)out)[i] = o;
}

extern "C" void kernel_launch(void* const* d_in, const int* in_sizes, int n_in,
                              void* d_out, int out_size, void* d_ws, size_t ws_size,
                              hipStream_t stream)
{
  const float* A  = (const float*)d_in[0];
  const float* B  = (const float*)d_in[1];
  const float* W1 = (const float*)d_in[2];
  const float* b1 = (const float*)d_in[3];
  const float* W2 = (const float*)d_in[4];
  const float* b2 = (const float*)d_in[5];
  float* out = (float*)d_out;

  char* ws = (char*)d_ws;
  _Float16* Af  = (_Float16*)(ws + 0);           // X = Af||Bf = (32768,768)
  _Float16* Bf  = (_Float16*)(ws + 25165824);
  _Float16* W1t = (_Float16*)(ws + 50331648);
  _Float16* W2t = (_Float16*)(ws + 51904512);
  // partials overwrite W1t/W2t (dead after gemm2; e-gemm runs later)
  float*    prm = (float*)   (ws + 50331648);
  float*    prs = (float*)   (ws + 50331648 + 524288);
  float*    pcm = (float*)   (ws + 50331648 + 1048576);
  float*    pcs = (float*)   (ws + 50331648 + 1572864);
  _Float16* fAB = (_Float16*)(ws + 54001664);    // (32768,1024)
  _Float16* P   = (_Float16*)(ws + 54001664);    // alias fAB (dead after e-gemm)
  _Float16* PT  = (_Float16*)(ws + 87556096);
  _Float16* h   = (_Float16*)(ws + 121110528);   // (32768,1024)
  float*    e   = (float*)   (ws + 121110528);   // alias h (dead after gemm2)
  _Float16* fA = fAB;
  _Float16* fB = fAB + 16777216;
  _Float16* At = Af;
  _Float16* Bt = Bf;

  dim3 blk(256);
  dim3 tblk(32, 8);

  cvt_f16_2<<<24576, blk, 0, stream>>>(A, B, Af, Bf, 3145728);
  // W1 (768,1024) and W2 (1024,1024) transposed+cvt in ONE launch
  transpose_cvt<<<dim3(32, 32, 2), tblk, 0, stream>>>(
      W1, W1t, W2, W2t, 768, 1024, 1, 1024, 1024);

  // h = relu([Af;Bf] @ W1 + b1)  (32768x1024), gm=256 gn=8
  gemm_k<768, true, false, _Float16><<<2048, blk, 0, stream>>>(
      Af, W1t, b1, h, 1024, 0, 0, 0, 256, 8, 1,
      nullptr, nullptr, nullptr, nullptr, nullptr, nullptr, nullptr, 0);
  // At/Bt (f16 (768,1024) per batch) — Af/Bf dead after gemm1
  transpose_cvt<<<dim3(24, 32, 32), tblk, 0, stream>>>(
      A, At, B, Bt, 1024, 768, 16, 1024, 768);
  // fAB = relu(h @ W2 + b2)
  gemm_k<1024, true, false, _Float16><<<2048, blk, 0, stream>>>(
      h, W2t, b2, fAB, 1024, 0, 0, 0, 256, 8, 1,
      nullptr, nullptr, nullptr, nullptr, nullptr, nullptr, nullptr, 0);

  // e = fA @ fB^T (batched fp32) + softmax partials in epilogue
  // (!BIASRELU -> 2 blocks/CU cap: one batch's fA+fB = 4MB = L2 per XCD)
  gemm_k<1024, false, true, float><<<1024, blk, 0, stream>>>(
      fA, fB, nullptr, e, 1024, 1048576L, 1048576L, 1048576L, 8, 8, 16,
      prm, prs, pcm, pcs, nullptr, nullptr, nullptr, 0);

  softmax_apply<<<dim3(16, 16, 16), blk, 0, stream>>>(e, prm, prs, pcm, pcs, P, PT);

  // beta = P @ Bt -> out[0:12582912]; alpha = PT @ At -> out[12582912:]
  // merged launch: gm=8 gn=6 gz=16 per half, shalf = 2*48 = 96
  gemm_k<1024, false, false, float><<<1536, blk, 0, stream>>>(
      P, Bt, nullptr, out, 768, 1048576L, 786432L, 786432L, 8, 6, 16,
      nullptr, nullptr, nullptr, nullptr, PT, At, out + 12582912, 96);
}